// Round 1
// baseline (1325.926 us; speedup 1.0000x reference)
//
#include <hip/hip_runtime.h>
#include <math.h>

#define IN_D 256
#define OUT_D 128
#define ED_D 64
#define NEG 0.2f

__device__ __forceinline__ unsigned fenc(float f) {
    unsigned u = __float_as_uint(f);
    return (u & 0x80000000u) ? ~u : (u | 0x80000000u);
}
__device__ __forceinline__ float fdec(unsigned x) {
    return (x & 0x80000000u) ? __uint_as_float(x & 0x7fffffffu) : __uint_as_float(~x);
}

// K0: fold ex_t branch of attention: u[k] = sum_j w3[j]*W_eatt[j][k]; c0 = w3.b_eatt + b_att
__global__ void k_prep(const float* __restrict__ W_att, const float* __restrict__ b_att,
                       const float* __restrict__ W_eatt, const float* __restrict__ b_eatt,
                       float* __restrict__ u, float* __restrict__ c0) {
    int k = threadIdx.x;  // 64 threads
    float acc = 0.f;
    for (int j = 0; j < ED_D; ++j) acc += W_att[256 + j] * W_eatt[j * ED_D + k];
    u[k] = acc;
    if (k == 0) {
        float c = 0.f;
        for (int j = 0; j < ED_D; ++j) c += W_att[256 + j] * b_eatt[j];
        c0[0] = c + b_att[0];
    }
}

// K1: z = nfeat @ W_fc^T + b_fc  [N,128]; also a_src[n]=z.w1, a_dst[n]=z.w2 via wave reduce.
// block 256: d = t&127 (output dim), g = t>>7 selects node octet; 16 nodes per block.
__global__ __launch_bounds__(256) void k_node(
        const float* __restrict__ nfeat, const float* __restrict__ W_fc,
        const float* __restrict__ b_fc, const float* __restrict__ W_att,
        float* __restrict__ z, float* __restrict__ asrc, float* __restrict__ adst, int n) {
    int t = threadIdx.x;
    int d = t & 127, g = t >> 7;
    int n0 = blockIdx.x * 16 + g * 8;
    float acc[8];
#pragma unroll
    for (int i = 0; i < 8; ++i) acc[i] = 0.f;
    int node[8];
#pragma unroll
    for (int i = 0; i < 8; ++i) { int nd = n0 + i; node[i] = nd < n ? nd : n - 1; }
    const float4* Wrow = (const float4*)(W_fc + (size_t)d * IN_D);
#pragma unroll 4
    for (int q = 0; q < 64; ++q) {
        float4 w4 = Wrow[q];
#pragma unroll
        for (int i = 0; i < 8; ++i) {
            float4 x4 = *(const float4*)(nfeat + (size_t)node[i] * IN_D + q * 4);
            acc[i] += w4.x * x4.x + w4.y * x4.y + w4.z * x4.z + w4.w * x4.w;
        }
    }
    float bb = b_fc[d];
    float w1d = W_att[d], w2d = W_att[128 + d];
#pragma unroll
    for (int i = 0; i < 8; ++i) {
        int nd = n0 + i;
        float zv = acc[i] + bb;
        if (nd < n) z[(size_t)nd * OUT_D + d] = zv;
        float p1 = zv * w1d, p2 = zv * w2d;
#pragma unroll
        for (int off = 32; off >= 1; off >>= 1) {
            p1 += __shfl_xor(p1, off);
            p2 += __shfl_xor(p2, off);
        }
        if ((t & 63) == 0 && nd < n) {
            atomicAdd(&asrc[nd], p1);
            atomicAdd(&adst[nd], p2);
        }
    }
}

// K2: per-edge attention logit + leaky_relu; atomicMax for segment max.
__global__ __launch_bounds__(256) void k_edge_score(
        const float* __restrict__ ex, const int* __restrict__ src, const int* __restrict__ dst,
        const float* __restrict__ asrc, const float* __restrict__ adst,
        const float* __restrict__ u, const float* __restrict__ c0,
        float* __restrict__ ebuf, unsigned* __restrict__ menc, int E) {
    int i = blockIdx.x * 256 + threadIdx.x;
    if (i >= E) return;
    const float4* exr = (const float4*)(ex + (size_t)i * ED_D);
    const float4* u4 = (const float4*)u;
    float acc = 0.f;
#pragma unroll
    for (int q = 0; q < 16; ++q) {
        float4 a = exr[q], b = u4[q];
        acc += a.x * b.x + a.y * b.y + a.z * b.z + a.w * b.w;
    }
    int s = src[i], t = dst[i];
    float e = acc + asrc[s] + adst[t] + c0[0];
    e = (e > 0.f) ? e : NEG * e;
    ebuf[i] = e;
    atomicMax(&menc[t], fenc(e));
}

// K4: w = exp(e - m[dst]); denom via atomicAdd. Overwrites ebuf with w.
__global__ __launch_bounds__(256) void k_edge_w(
        const int* __restrict__ dst, const unsigned* __restrict__ menc,
        float* __restrict__ ebuf, float* __restrict__ denom, int E) {
    int i = blockIdx.x * 256 + threadIdx.x;
    if (i >= E) return;
    int t = dst[i];
    float m = fdec(menc[t]);
    float w = expf(ebuf[i] - m);
    ebuf[i] = w;
    atomicAdd(&denom[t], w);
}

// K5: alpha = w/denom[dst]; ez = W_edge@ex + b_edge on the fly (W_edge rows in regs);
// scatter-add alpha*(z_src+ez) into h. 128 threads per edge (d = t&127), 2 edges/block-iter.
__global__ __launch_bounds__(256) void k_scatter(
        const float* __restrict__ ex, const int* __restrict__ src, const int* __restrict__ dst,
        const float* __restrict__ wbuf, const float* __restrict__ denom,
        const float* __restrict__ z, const float* __restrict__ W_edge, const float* __restrict__ b_edge,
        float* __restrict__ h, float* __restrict__ alpha_out, int E) {
    int t = threadIdx.x;
    int d = t & 127, g = t >> 7;
    float4 wreg[16];
#pragma unroll
    for (int q = 0; q < 16; ++q) wreg[q] = *(const float4*)(W_edge + (size_t)d * ED_D + q * 4);
    float be = b_edge[d];
    int stride = gridDim.x * 2;
    for (int edge = blockIdx.x * 2 + g; edge < E; edge += stride) {
        int s = src[edge], dd = dst[edge];
        float wv = wbuf[edge];
        float alpha = wv / denom[dd];
        const float4* exr = (const float4*)(ex + (size_t)edge * ED_D);
        float acc = be;
#pragma unroll
        for (int q = 0; q < 16; ++q) {
            float4 x4 = exr[q];
            acc += wreg[q].x * x4.x + wreg[q].y * x4.y + wreg[q].z * x4.z + wreg[q].w * x4.w;
        }
        float zs = z[(size_t)s * OUT_D + d];
        atomicAdd(&h[(size_t)dd * OUT_D + d], alpha * (zs + acc));
        if (d == 0) alpha_out[edge] = alpha;
    }
}

extern "C" void kernel_launch(void* const* d_in, const int* in_sizes, int n_in,
                              void* d_out, int out_size, void* d_ws, size_t ws_size,
                              hipStream_t stream) {
    const float* nfeat = (const float*)d_in[0];
    const float* ex    = (const float*)d_in[1];
    const int*   src   = (const int*)d_in[2];
    const int*   dst   = (const int*)d_in[3];
    const float* W_fc  = (const float*)d_in[4];
    const float* b_fc  = (const float*)d_in[5];
    const float* W_att = (const float*)d_in[6];
    const float* b_att = (const float*)d_in[7];
    const float* W_edge = (const float*)d_in[8];
    const float* b_edge = (const float*)d_in[9];
    const float* W_eatt = (const float*)d_in[10];
    const float* b_eatt = (const float*)d_in[11];
    int N = in_sizes[0] / IN_D;
    int E = in_sizes[2];

    float* h_out = (float*)d_out;
    float* alpha_out = h_out + (size_t)N * OUT_D;

    char* w = (char*)d_ws;
    auto alloc = [&](size_t bytes) { char* p = w; w += (bytes + 255) & ~255ull; return p; };
    float* z       = (float*)alloc((size_t)N * OUT_D * 4);
    float* asrc    = (float*)alloc((size_t)N * 4);
    float* adst    = (float*)alloc((size_t)N * 4);
    float* ebuf    = (float*)alloc((size_t)E * 4);
    unsigned* menc = (unsigned*)alloc((size_t)N * 4);
    float* denom   = (float*)alloc((size_t)N * 4);
    float* u       = (float*)alloc(64 * 4);
    float* c0      = (float*)alloc(4);

    hipMemsetAsync(h_out, 0, (size_t)N * OUT_D * 4, stream);
    hipMemsetAsync(asrc, 0, (size_t)N * 4, stream);
    hipMemsetAsync(adst, 0, (size_t)N * 4, stream);
    hipMemsetAsync(menc, 0, (size_t)N * 4, stream);
    hipMemsetAsync(denom, 0, (size_t)N * 4, stream);

    k_prep<<<1, 64, 0, stream>>>(W_att, b_att, W_eatt, b_eatt, u, c0);
    k_node<<<(N + 15) / 16, 256, 0, stream>>>(nfeat, W_fc, b_fc, W_att, z, asrc, adst, N);
    k_edge_score<<<(E + 255) / 256, 256, 0, stream>>>(ex, src, dst, asrc, adst, u, c0, ebuf, menc, E);
    k_edge_w<<<(E + 255) / 256, 256, 0, stream>>>(dst, menc, ebuf, denom, E);
    k_scatter<<<2048, 256, 0, stream>>>(ex, src, dst, ebuf, denom, z, W_edge, b_edge, h_out, alpha_out, E);
}

// Round 2
// 941.709 us; speedup vs baseline: 1.4080x; 1.4080x over previous
//
#include <hip/hip_runtime.h>
#include <math.h>
#include <float.h>

#define IN_D 256
#define OUT_D 128
#define ED_D 64
#define NEG 0.2f

// K0: fold ex_t branch of attention: u[k] = sum_j w3[j]*W_eatt[j][k]; c0 = w3.b_eatt + b_att
__global__ void k_prep(const float* __restrict__ W_att, const float* __restrict__ b_att,
                       const float* __restrict__ W_eatt, const float* __restrict__ b_eatt,
                       float* __restrict__ u, float* __restrict__ c0) {
    int k = threadIdx.x;  // 64 threads
    float acc = 0.f;
    for (int j = 0; j < ED_D; ++j) acc += W_att[256 + j] * W_eatt[j * ED_D + k];
    u[k] = acc;
    if (k == 0) {
        float c = 0.f;
        for (int j = 0; j < ED_D; ++j) c += W_att[256 + j] * b_eatt[j];
        c0[0] = c + b_att[0];
    }
}

// K1: z = nfeat @ W_fc^T + b_fc  [N,128]; also a_src[n]=z.w1, a_dst[n]=z.w2 via wave reduce.
__global__ __launch_bounds__(256) void k_node(
        const float* __restrict__ nfeat, const float* __restrict__ W_fc,
        const float* __restrict__ b_fc, const float* __restrict__ W_att,
        float* __restrict__ z, float* __restrict__ asrc, float* __restrict__ adst, int n) {
    int t = threadIdx.x;
    int d = t & 127, g = t >> 7;
    int n0 = blockIdx.x * 16 + g * 8;
    float acc[8];
#pragma unroll
    for (int i = 0; i < 8; ++i) acc[i] = 0.f;
    int node[8];
#pragma unroll
    for (int i = 0; i < 8; ++i) { int nd = n0 + i; node[i] = nd < n ? nd : n - 1; }
    const float4* Wrow = (const float4*)(W_fc + (size_t)d * IN_D);
#pragma unroll 4
    for (int q = 0; q < 64; ++q) {
        float4 w4 = Wrow[q];
#pragma unroll
        for (int i = 0; i < 8; ++i) {
            float4 x4 = *(const float4*)(nfeat + (size_t)node[i] * IN_D + q * 4);
            acc[i] += w4.x * x4.x + w4.y * x4.y + w4.z * x4.z + w4.w * x4.w;
        }
    }
    float bb = b_fc[d];
    float w1d = W_att[d], w2d = W_att[128 + d];
#pragma unroll
    for (int i = 0; i < 8; ++i) {
        int nd = n0 + i;
        float zv = acc[i] + bb;
        if (nd < n) z[(size_t)nd * OUT_D + d] = zv;
        float p1 = zv * w1d, p2 = zv * w2d;
#pragma unroll
        for (int off = 32; off >= 1; off >>= 1) {
            p1 += __shfl_xor(p1, off);
            p2 += __shfl_xor(p2, off);
        }
        if ((t & 63) == 0 && nd < n) {
            atomicAdd(&asrc[nd], p1);
            atomicAdd(&adst[nd], p2);
        }
    }
}

// K2: per-edge attention logit + leaky_relu -> ebuf; histogram of dst -> cnt.
__global__ __launch_bounds__(256) void k_score_hist(
        const float* __restrict__ ex, const int* __restrict__ src, const int* __restrict__ dst,
        const float* __restrict__ asrc, const float* __restrict__ adst,
        const float* __restrict__ u, const float* __restrict__ c0,
        float* __restrict__ ebuf, int* __restrict__ cnt, int E) {
    int i = blockIdx.x * 256 + threadIdx.x;
    if (i >= E) return;
    const float4* exr = (const float4*)(ex + (size_t)i * ED_D);
    const float4* u4 = (const float4*)u;
    float acc = 0.f;
#pragma unroll
    for (int q = 0; q < 16; ++q) {
        float4 a = exr[q], b = u4[q];
        acc += a.x * b.x + a.y * b.y + a.z * b.z + a.w * b.w;
    }
    int s = src[i], t = dst[i];
    float e = acc + asrc[s] + adst[t] + c0[0];
    e = (e > 0.f) ? e : NEG * e;
    ebuf[i] = e;
    atomicAdd(&cnt[t], 1);
}

// K3: exclusive scan of cnt -> rowptr (single block, blocked scan).
__global__ __launch_bounds__(1024) void k_scan(const int* __restrict__ cnt,
                                               int* __restrict__ rowptr, int N) {
    int t = threadIdx.x;
    int per = (N + 1023) / 1024;
    int b0 = t * per;
    int b1 = b0 + per;
    if (b0 > N) b0 = N;
    if (b1 > N) b1 = N;
    int s = 0;
    for (int i = b0; i < b1; ++i) s += cnt[i];
    int wl = t & 63, w = t >> 6;
    int v = s;
#pragma unroll
    for (int off = 1; off < 64; off <<= 1) {
        int a = __shfl_up(v, off);
        if (wl >= off) v += a;
    }
    __shared__ int wsum[16], woff[16];
    if (wl == 63) wsum[w] = v;
    __syncthreads();
    if (t == 0) { int r = 0; for (int i = 0; i < 16; ++i) { woff[i] = r; r += wsum[i]; } }
    __syncthreads();
    int run = woff[w] + v - s;  // exclusive prefix for this thread's chunk
    for (int i = b0; i < b1; ++i) { rowptr[i] = run; run += cnt[i]; }
    if (t == 1023) rowptr[N] = run;
}

// K4: bucket edge ids by dst -> eid (CSR).
__global__ __launch_bounds__(256) void k_fill(const int* __restrict__ dst,
                                              const int* __restrict__ rowptr,
                                              int* __restrict__ fill, int* __restrict__ eid, int E) {
    int i = blockIdx.x * 256 + threadIdx.x;
    if (i >= E) return;
    int d = dst[i];
    int pos = rowptr[d] + atomicAdd(&fill[d], 1);
    eid[pos] = i;
}

// K5: per-dst-node softmax + accumulation. 128 threads = 1 node.
// h[n] = sum_e alpha*z[src] + W_edge @ (sum_e alpha*ex[e]) + b_edge   (since sum alpha = 1)
__global__ __launch_bounds__(128) void k_gather(
        const float* __restrict__ ex, const int* __restrict__ src,
        const int* __restrict__ rowptr, const int* __restrict__ eid,
        const float* __restrict__ ebuf, const float* __restrict__ z,
        const float* __restrict__ W_edge, const float* __restrict__ b_edge,
        float* __restrict__ h, float* __restrict__ alpha_out, int N) {
    int l = threadIdx.x;      // output dim 0..127
    int wl = l & 63;
    bool w0 = (l < 64);
    float4 wreg[16];
#pragma unroll
    for (int q = 0; q < 16; ++q) wreg[q] = *(const float4*)(W_edge + (size_t)l * ED_D + q * 4);
    float be = b_edge[l];
    __shared__ float sx[2][64];
    int par = 0;
    for (int n = blockIdx.x; n < N; n += gridDim.x) {
        int beg = rowptr[n], end = rowptr[n + 1];
        if (end == beg) {
            h[(size_t)n * OUT_D + l] = 0.f;   // empty segment: reference gives 0
            continue;
        }
        // softmax stats (redundant per wave, no cross-wave sync needed)
        float m = -FLT_MAX;
        for (int i = beg + wl; i < end; i += 64) m = fmaxf(m, ebuf[eid[i]]);
#pragma unroll
        for (int off = 32; off >= 1; off >>= 1) m = fmaxf(m, __shfl_xor(m, off));
        float sden = 0.f;
        for (int i = beg + wl; i < end; i += 64) sden += expf(ebuf[eid[i]] - m);
#pragma unroll
        for (int off = 32; off >= 1; off >>= 1) sden += __shfl_xor(sden, off);
        float rden = 1.f / sden;
        if (w0) {
            for (int i = beg + wl; i < end; i += 64) {
                int e = eid[i];
                alpha_out[e] = expf(ebuf[e] - m) * rden;
            }
        }
        // accumulate acc_z[l] = sum alpha*z[src][l];  acc_x[wl] = sum alpha*ex[e][wl] (wave 0)
        float accz = 0.f, accx = 0.f;
#pragma unroll 2
        for (int i = beg; i < end; ++i) {
            int e = eid[i];                      // uniform -> broadcast load
            float al = expf(ebuf[e] - m) * rden; // broadcast load + exp
            int s = src[e];                      // broadcast load
            accz += al * z[(size_t)s * OUT_D + l];  // coalesced 128-lane row read
            if (w0) accx += al * ex[(size_t)e * ED_D + wl];  // coalesced 64-lane row read
        }
        if (w0) sx[par][wl] = accx;
        __syncthreads();
        float ax = sx[par][wl];
        float hv = accz + be;
#pragma unroll
        for (int q = 0; q < 16; ++q) {
            hv += wreg[q].x * __shfl(ax, q * 4 + 0);
            hv += wreg[q].y * __shfl(ax, q * 4 + 1);
            hv += wreg[q].z * __shfl(ax, q * 4 + 2);
            hv += wreg[q].w * __shfl(ax, q * 4 + 3);
        }
        h[(size_t)n * OUT_D + l] = hv;
        par ^= 1;
    }
}

extern "C" void kernel_launch(void* const* d_in, const int* in_sizes, int n_in,
                              void* d_out, int out_size, void* d_ws, size_t ws_size,
                              hipStream_t stream) {
    const float* nfeat = (const float*)d_in[0];
    const float* ex    = (const float*)d_in[1];
    const int*   src   = (const int*)d_in[2];
    const int*   dst   = (const int*)d_in[3];
    const float* W_fc  = (const float*)d_in[4];
    const float* b_fc  = (const float*)d_in[5];
    const float* W_att = (const float*)d_in[6];
    const float* b_att = (const float*)d_in[7];
    const float* W_edge = (const float*)d_in[8];
    const float* b_edge = (const float*)d_in[9];
    const float* W_eatt = (const float*)d_in[10];
    const float* b_eatt = (const float*)d_in[11];
    int N = in_sizes[0] / IN_D;
    int E = in_sizes[2];

    float* h_out = (float*)d_out;
    float* alpha_out = h_out + (size_t)N * OUT_D;

    char* w = (char*)d_ws;
    auto alloc = [&](size_t bytes) { char* p = w; w += (bytes + 255) & ~255ull; return p; };
    float* z     = (float*)alloc((size_t)N * OUT_D * 4);
    float* asrc  = (float*)alloc((size_t)N * 4);
    float* adst  = (float*)alloc((size_t)N * 4);
    float* ebuf  = (float*)alloc((size_t)E * 4);
    int* cnt     = (int*)alloc((size_t)N * 4);
    int* rowptr  = (int*)alloc(((size_t)N + 1) * 4);
    int* fill    = (int*)alloc((size_t)N * 4);
    int* eid     = (int*)alloc((size_t)E * 4);
    float* u     = (float*)alloc(64 * 4);
    float* c0    = (float*)alloc(4);

    hipMemsetAsync(asrc, 0, (size_t)N * 4, stream);
    hipMemsetAsync(adst, 0, (size_t)N * 4, stream);
    hipMemsetAsync(cnt, 0, (size_t)N * 4, stream);
    hipMemsetAsync(fill, 0, (size_t)N * 4, stream);

    k_prep<<<1, 64, 0, stream>>>(W_att, b_att, W_eatt, b_eatt, u, c0);
    k_node<<<(N + 15) / 16, 256, 0, stream>>>(nfeat, W_fc, b_fc, W_att, z, asrc, adst, N);
    k_score_hist<<<(E + 255) / 256, 256, 0, stream>>>(ex, src, dst, asrc, adst, u, c0, ebuf, cnt, E);
    k_scan<<<1, 1024, 0, stream>>>(cnt, rowptr, N);
    k_fill<<<(E + 255) / 256, 256, 0, stream>>>(dst, rowptr, fill, eid, E);
    k_gather<<<4096, 128, 0, stream>>>(ex, src, rowptr, eid, ebuf, z, W_edge, b_edge,
                                       h_out, alpha_out, N);
}

// Round 3
// 818.581 us; speedup vs baseline: 1.6198x; 1.1504x over previous
//
#include <hip/hip_runtime.h>
#include <math.h>
#include <float.h>

#define IN_D 256
#define OUT_D 128
#define ED_D 64
#define NEG 0.2f

__device__ __forceinline__ unsigned fenc(float f) {
    unsigned u = __float_as_uint(f);
    return (u & 0x80000000u) ? ~u : (u | 0x80000000u);
}
__device__ __forceinline__ float fdec(unsigned x) {
    return (x & 0x80000000u) ? __uint_as_float(x & 0x7fffffffu) : __uint_as_float(~x);
}

// K0 (128 threads): u[k] = sum_j w3[j]*W_eatt[j][k]; c0 = w3.b_eatt + b_att;
// Wt[k*128+l] = W_edge[l*64+k]  (transposed copy for k_xmm's LDS tile)
__global__ void k_prep(const float* __restrict__ W_att, const float* __restrict__ b_att,
                       const float* __restrict__ W_eatt, const float* __restrict__ b_eatt,
                       const float* __restrict__ W_edge,
                       float* __restrict__ u, float* __restrict__ c0, float* __restrict__ Wt) {
    int t = threadIdx.x;  // 0..127
    if (t < ED_D) {
        float acc = 0.f;
        for (int j = 0; j < ED_D; ++j) acc += W_att[256 + j] * W_eatt[j * ED_D + t];
        u[t] = acc;
    }
    for (int k = 0; k < ED_D; ++k) Wt[k * OUT_D + t] = W_edge[t * ED_D + k];
    if (t == 0) {
        float c = 0.f;
        for (int j = 0; j < ED_D; ++j) c += W_att[256 + j] * b_eatt[j];
        c0[0] = c + b_att[0];
    }
}

// K1: z = nfeat @ W_fc^T + b_fc  [N,128]; also a_src[n]=z.w1, a_dst[n]=z.w2 via wave reduce.
__global__ __launch_bounds__(256) void k_node(
        const float* __restrict__ nfeat, const float* __restrict__ W_fc,
        const float* __restrict__ b_fc, const float* __restrict__ W_att,
        float* __restrict__ z, float* __restrict__ asrc, float* __restrict__ adst, int n) {
    int t = threadIdx.x;
    int d = t & 127, g = t >> 7;
    int n0 = blockIdx.x * 16 + g * 8;
    float acc[8];
#pragma unroll
    for (int i = 0; i < 8; ++i) acc[i] = 0.f;
    int node[8];
#pragma unroll
    for (int i = 0; i < 8; ++i) { int nd = n0 + i; node[i] = nd < n ? nd : n - 1; }
    const float4* Wrow = (const float4*)(W_fc + (size_t)d * IN_D);
#pragma unroll 4
    for (int q = 0; q < 64; ++q) {
        float4 w4 = Wrow[q];
#pragma unroll
        for (int i = 0; i < 8; ++i) {
            float4 x4 = *(const float4*)(nfeat + (size_t)node[i] * IN_D + q * 4);
            acc[i] += w4.x * x4.x + w4.y * x4.y + w4.z * x4.z + w4.w * x4.w;
        }
    }
    float bb = b_fc[d];
    float w1d = W_att[d], w2d = W_att[128 + d];
#pragma unroll
    for (int i = 0; i < 8; ++i) {
        int nd = n0 + i;
        float zv = acc[i] + bb;
        if (nd < n) z[(size_t)nd * OUT_D + d] = zv;
        float p1 = zv * w1d, p2 = zv * w2d;
#pragma unroll
        for (int off = 32; off >= 1; off >>= 1) {
            p1 += __shfl_xor(p1, off);
            p2 += __shfl_xor(p2, off);
        }
        if ((t & 63) == 0 && nd < n) {
            atomicAdd(&asrc[nd], p1);
            atomicAdd(&adst[nd], p2);
        }
    }
}

// K2: per-edge logit + leaky_relu -> ebuf; segment max via atomicMax; dst histogram.
__global__ __launch_bounds__(256) void k_score(
        const float* __restrict__ ex, const int* __restrict__ src, const int* __restrict__ dst,
        const float* __restrict__ asrc, const float* __restrict__ adst,
        const float* __restrict__ u, const float* __restrict__ c0,
        float* __restrict__ ebuf, unsigned* __restrict__ menc, int* __restrict__ cnt, int E) {
    int i = blockIdx.x * 256 + threadIdx.x;
    if (i >= E) return;
    const float4* exr = (const float4*)(ex + (size_t)i * ED_D);
    const float4* u4 = (const float4*)u;
    float acc = 0.f;
#pragma unroll
    for (int q = 0; q < 16; ++q) {
        float4 a = exr[q], b = u4[q];
        acc += a.x * b.x + a.y * b.y + a.z * b.z + a.w * b.w;
    }
    int s = src[i], t = dst[i];
    float e = acc + asrc[s] + adst[t] + c0[0];
    e = (e > 0.f) ? e : NEG * e;
    ebuf[i] = e;
    atomicMax(&menc[t], fenc(e));
    atomicAdd(&cnt[t], 1);
}

// K3: exclusive scan of cnt -> rowptr (single block).
__global__ __launch_bounds__(1024) void k_scan(const int* __restrict__ cnt,
                                               int* __restrict__ rowptr, int N) {
    int t = threadIdx.x;
    int per = (N + 1023) / 1024;
    int b0 = t * per, b1 = b0 + per;
    if (b0 > N) b0 = N;
    if (b1 > N) b1 = N;
    int s = 0;
    for (int i = b0; i < b1; ++i) s += cnt[i];
    int wl = t & 63, w = t >> 6;
    int v = s;
#pragma unroll
    for (int off = 1; off < 64; off <<= 1) {
        int a = __shfl_up(v, off);
        if (wl >= off) v += a;
    }
    __shared__ int wsum[16], woff[16];
    if (wl == 63) wsum[w] = v;
    __syncthreads();
    if (t == 0) { int r = 0; for (int i = 0; i < 16; ++i) { woff[i] = r; r += wsum[i]; } }
    __syncthreads();
    int run = woff[w] + v - s;
    for (int i = b0; i < b1; ++i) { rowptr[i] = run; run += cnt[i]; }
    if (t == 1023) rowptr[N] = run;
}

// K4: CSR bucket + w=exp(e-m) once + denom. Writes src_csr[pos], {w,e}->we_csr[pos].
__global__ __launch_bounds__(256) void k_fill2(
        const int* __restrict__ src, const int* __restrict__ dst,
        const float* __restrict__ ebuf, const unsigned* __restrict__ menc,
        const int* __restrict__ rowptr, int* __restrict__ fill,
        float* __restrict__ denom, int* __restrict__ src_csr, int2* __restrict__ we_csr, int E) {
    int i = blockIdx.x * 256 + threadIdx.x;
    if (i >= E) return;
    int d = dst[i];
    int pos = rowptr[d] + atomicAdd(&fill[d], 1);
    float w = expf(ebuf[i] - fdec(menc[d]));
    atomicAdd(&denom[d], w);
    src_csr[pos] = src[i];
    we_csr[pos] = make_int2(__float_as_int(w), i);
}

// K5: wave-per-node weighted accumulation. Meta loaded coalesced (64 edges/shot),
// broadcast via shfl; 4 independent row loads in flight per unrolled step.
__global__ __launch_bounds__(256) void k_gather(
        const float2* __restrict__ zf2, const float* __restrict__ ex,
        const int* __restrict__ src_csr, const int2* __restrict__ we_csr,
        const int* __restrict__ rowptr, const float* __restrict__ denom,
        float2* __restrict__ h2, float* __restrict__ alpha_out, float* __restrict__ xsum, int N) {
    int lane = threadIdx.x & 63;
    int wid = blockIdx.x * 4 + (threadIdx.x >> 6);
    int nw = gridDim.x * 4;
    for (int n = wid; n < N; n += nw) {
        int beg = rowptr[n], end = rowptr[n + 1];
        float rden = 1.f / denom[n];
        float2 accz = make_float2(0.f, 0.f);
        float accx = 0.f;
        for (int c = beg; c < end; c += 64) {
            int mcnt = end - c;
            if (mcnt > 64) mcnt = 64;
            float al = 0.f; int sl = 0, el = 0;
            if (lane < mcnt) {
                int2 me = we_csr[c + lane];
                al = __int_as_float(me.x) * rden;
                el = me.y;
                sl = src_csr[c + lane];
                alpha_out[el] = al;
            }
            int j = 0;
            for (; j + 4 <= mcnt; j += 4) {
                float a[4]; int s[4], e[4];
#pragma unroll
                for (int q = 0; q < 4; ++q) {
                    a[q] = __shfl(al, j + q);
                    s[q] = __shfl(sl, j + q);
                    e[q] = __shfl(el, j + q);
                }
                float2 zv[4]; float xv[4];
#pragma unroll
                for (int q = 0; q < 4; ++q) {
                    zv[q] = zf2[(size_t)s[q] * 64 + lane];
                    xv[q] = ex[(size_t)e[q] * 64 + lane];
                }
#pragma unroll
                for (int q = 0; q < 4; ++q) {
                    accz.x = fmaf(a[q], zv[q].x, accz.x);
                    accz.y = fmaf(a[q], zv[q].y, accz.y);
                    accx = fmaf(a[q], xv[q], accx);
                }
            }
            for (; j < mcnt; ++j) {
                float aq = __shfl(al, j);
                int sq = __shfl(sl, j), eq = __shfl(el, j);
                float2 zq = zf2[(size_t)sq * 64 + lane];
                float xq = ex[(size_t)eq * 64 + lane];
                accz.x = fmaf(aq, zq.x, accz.x);
                accz.y = fmaf(aq, zq.y, accz.y);
                accx = fmaf(aq, xq, accx);
            }
        }
        h2[(size_t)n * 64 + lane] = accz;
        xsum[(size_t)n * 64 + lane] = accx;
    }
}

// K6: h = accz + Wt@xsum + b_edge (or 0 for empty segments). Wt staged in LDS.
__global__ __launch_bounds__(128) void k_xmm(
        const float* __restrict__ Wt, const float* __restrict__ b_edge,
        const float* __restrict__ xsum, const float* __restrict__ denom,
        float* __restrict__ h, int N) {
    __shared__ float wt[ED_D * OUT_D];
    int t = threadIdx.x;
    for (int i = t; i < ED_D * OUT_D; i += 128) wt[i] = Wt[i];
    __syncthreads();
    int lane = t & 63;
    float be = b_edge[t];
    for (int n = blockIdx.x; n < N; n += gridDim.x) {
        float xk = xsum[(size_t)n * ED_D + lane];
        float dn = denom[n];
        float hv = h[(size_t)n * OUT_D + t];
#pragma unroll 8
        for (int k = 0; k < ED_D; ++k) {
            hv = fmaf(wt[k * OUT_D + t], __shfl(xk, k), hv);
        }
        h[(size_t)n * OUT_D + t] = (dn != 0.f) ? (hv + be) : 0.f;
    }
}

extern "C" void kernel_launch(void* const* d_in, const int* in_sizes, int n_in,
                              void* d_out, int out_size, void* d_ws, size_t ws_size,
                              hipStream_t stream) {
    const float* nfeat = (const float*)d_in[0];
    const float* ex    = (const float*)d_in[1];
    const int*   src   = (const int*)d_in[2];
    const int*   dst   = (const int*)d_in[3];
    const float* W_fc  = (const float*)d_in[4];
    const float* b_fc  = (const float*)d_in[5];
    const float* W_att = (const float*)d_in[6];
    const float* b_att = (const float*)d_in[7];
    const float* W_edge = (const float*)d_in[8];
    const float* b_edge = (const float*)d_in[9];
    const float* W_eatt = (const float*)d_in[10];
    const float* b_eatt = (const float*)d_in[11];
    int N = in_sizes[0] / IN_D;
    int E = in_sizes[2];

    float* h_out = (float*)d_out;
    float* alpha_out = h_out + (size_t)N * OUT_D;

    char* w = (char*)d_ws;
    auto alloc = [&](size_t bytes) { char* p = w; w += (bytes + 255) & ~255ull; return p; };
    float* z      = (float*)alloc((size_t)N * OUT_D * 4);
    float* asrc   = (float*)alloc((size_t)N * 4);
    float* adst   = (float*)alloc((size_t)N * 4);
    float* ebuf   = (float*)alloc((size_t)E * 4);
    int* cnt      = (int*)alloc((size_t)N * 4);
    int* rowptr   = (int*)alloc(((size_t)N + 1) * 4);
    int* fill     = (int*)alloc((size_t)N * 4);
    unsigned* menc= (unsigned*)alloc((size_t)N * 4);
    float* denom  = (float*)alloc((size_t)N * 4);
    int* src_csr  = (int*)alloc((size_t)E * 4);
    int2* we_csr  = (int2*)alloc((size_t)E * 8);
    float* xsum   = (float*)alloc((size_t)N * ED_D * 4);
    float* Wt     = (float*)alloc((size_t)ED_D * OUT_D * 4);
    float* u      = (float*)alloc(64 * 4);
    float* c0     = (float*)alloc(4);

    hipMemsetAsync(asrc, 0, (size_t)N * 4, stream);
    hipMemsetAsync(adst, 0, (size_t)N * 4, stream);
    hipMemsetAsync(cnt, 0, (size_t)N * 4, stream);
    hipMemsetAsync(fill, 0, (size_t)N * 4, stream);
    hipMemsetAsync(menc, 0, (size_t)N * 4, stream);
    hipMemsetAsync(denom, 0, (size_t)N * 4, stream);

    k_prep<<<1, 128, 0, stream>>>(W_att, b_att, W_eatt, b_eatt, W_edge, u, c0, Wt);
    k_node<<<(N + 15) / 16, 256, 0, stream>>>(nfeat, W_fc, b_fc, W_att, z, asrc, adst, N);
    k_score<<<(E + 255) / 256, 256, 0, stream>>>(ex, src, dst, asrc, adst, u, c0, ebuf, menc, cnt, E);
    k_scan<<<1, 1024, 0, stream>>>(cnt, rowptr, N);
    k_fill2<<<(E + 255) / 256, 256, 0, stream>>>(src, dst, ebuf, menc, rowptr, fill, denom,
                                                 src_csr, we_csr, E);
    k_gather<<<(N + 3) / 4, 256, 0, stream>>>((const float2*)z, ex, src_csr, we_csr, rowptr,
                                              denom, (float2*)h_out, alpha_out, xsum, N);
    k_xmm<<<2048, 128, 0, stream>>>(Wt, b_edge, xsum, denom, h_out, N);
}

// Round 4
// 524.261 us; speedup vs baseline: 2.5291x; 1.5614x over previous
//
#include <hip/hip_runtime.h>
#include <math.h>
#include <float.h>

#define IN_D 256
#define OUT_D 128
#define ED_D 64
#define NEG 0.2f

__device__ __forceinline__ unsigned fenc(float f) {
    unsigned u = __float_as_uint(f);
    return (u & 0x80000000u) ? ~u : (u | 0x80000000u);
}
__device__ __forceinline__ float fdec(unsigned x) {
    return (x & 0x80000000u) ? __uint_as_float(x & 0x7fffffffu) : __uint_as_float(~x);
}

// K0 (128 threads): u[k] = sum_j w3[j]*W_eatt[j][k]; c0 = w3.b_eatt + b_att;
// Wt[k*128+l] = W_edge[l*64+k]  (transposed W_edge for k_xmm)
__global__ void k_prep(const float* __restrict__ W_att, const float* __restrict__ b_att,
                       const float* __restrict__ W_eatt, const float* __restrict__ b_eatt,
                       const float* __restrict__ W_edge,
                       float* __restrict__ u, float* __restrict__ c0, float* __restrict__ Wt) {
    int t = threadIdx.x;  // 0..127
    if (t < ED_D) {
        float acc = 0.f;
        for (int j = 0; j < ED_D; ++j) acc += W_att[256 + j] * W_eatt[j * ED_D + t];
        u[t] = acc;
    }
    for (int k = 0; k < ED_D; ++k) Wt[k * OUT_D + t] = W_edge[t * ED_D + k];
    if (t == 0) {
        float c = 0.f;
        for (int j = 0; j < ED_D; ++j) c += W_att[256 + j] * b_eatt[j];
        c0[0] = c + b_att[0];
    }
}

// K0b: Wt_fc[k][d] = W_fc[d][k]   (256x128 transpose so GEMM B-loads coalesce)
__global__ __launch_bounds__(256) void k_tr(const float* __restrict__ W_fc,
                                            float* __restrict__ Wt_fc) {
    int idx = blockIdx.x * 256 + threadIdx.x;   // 32768 total
    int k = idx >> 7, d = idx & 127;
    Wt_fc[idx] = W_fc[d * IN_D + k];
}

// K1: tiled f32 GEMM  z = nfeat @ W_fc^T + b_fc  [N,128]
// BM=128, BN=128, BK=32; 256 threads; 8x8 register tile per thread.
// Epilogue: asrc[m] = z[m].w1, adst[m] = z[m].w2 via in-wave shuffle reduce (plain stores).
__global__ __launch_bounds__(256) void k_node(
        const float* __restrict__ nfeat, const float* __restrict__ Wt_fc,
        const float* __restrict__ b_fc, const float* __restrict__ W_att,
        float* __restrict__ z, float* __restrict__ asrc, float* __restrict__ adst, int n) {
    __shared__ float sa[32][130];   // k-major A tile (pad: 2-way conflict = free)
    __shared__ float sb[32][128];   // k-major B tile
    int t = threadIdx.x;
    int tx = t & 15, ty = t >> 4;   // tx: n-group, ty: m-group
    int row_base = blockIdx.x * 128;

    float acc[8][8];
#pragma unroll
    for (int i = 0; i < 8; ++i)
#pragma unroll
        for (int j = 0; j < 8; ++j) acc[i][j] = 0.f;

    int ar = t >> 3, af = t & 7;        // A loader: row (32/pass), f4-col
    int bk = t >> 5, bn = t & 31;       // B loader: kk (8/pass), f4-col

    for (int k0 = 0; k0 < IN_D; k0 += 32) {
#pragma unroll
        for (int p = 0; p < 4; ++p) {
            int r = ar + p * 32;
            int node = row_base + r; if (node >= n) node = n - 1;
            float4 v = *(const float4*)(nfeat + (size_t)node * IN_D + k0 + af * 4);
            sa[af * 4 + 0][r] = v.x;
            sa[af * 4 + 1][r] = v.y;
            sa[af * 4 + 2][r] = v.z;
            sa[af * 4 + 3][r] = v.w;
        }
#pragma unroll
        for (int p = 0; p < 4; ++p) {
            int kk = bk + p * 8;
            float4 v = *(const float4*)(Wt_fc + (size_t)(k0 + kk) * 128 + bn * 4);
            *(float4*)&sb[kk][bn * 4] = v;
        }
        __syncthreads();
#pragma unroll 8
        for (int kk = 0; kk < 32; ++kk) {
            float a0[8], b0[8];
            *(float4*)&a0[0] = *(const float4*)&sa[kk][ty * 8];
            *(float4*)&a0[4] = *(const float4*)&sa[kk][ty * 8 + 4];
            *(float4*)&b0[0] = *(const float4*)&sb[kk][tx * 8];
            *(float4*)&b0[4] = *(const float4*)&sb[kk][tx * 8 + 4];
#pragma unroll
            for (int i = 0; i < 8; ++i)
#pragma unroll
                for (int j = 0; j < 8; ++j)
                    acc[i][j] = fmaf(a0[i], b0[j], acc[i][j]);
        }
        __syncthreads();
    }

    // epilogue
    float w1v[8], w2v[8], bf[8];
#pragma unroll
    for (int j = 0; j < 8; ++j) {
        int nn = tx * 8 + j;
        w1v[j] = W_att[nn];
        w2v[j] = W_att[128 + nn];
        bf[j] = b_fc[nn];
    }
#pragma unroll
    for (int i = 0; i < 8; ++i) {
        int m = row_base + ty * 8 + i;
        bool ok = (m < n);
        float zv[8];
        float p1 = 0.f, p2 = 0.f;
#pragma unroll
        for (int j = 0; j < 8; ++j) {
            zv[j] = acc[i][j] + bf[j];
            p1 = fmaf(zv[j], w1v[j], p1);
            p2 = fmaf(zv[j], w2v[j], p2);
        }
#pragma unroll
        for (int off = 1; off <= 8; off <<= 1) {
            p1 += __shfl_xor(p1, off);
            p2 += __shfl_xor(p2, off);
        }
        if (ok) {
            float* zr = z + (size_t)m * OUT_D + tx * 8;
            *(float4*)zr = make_float4(zv[0], zv[1], zv[2], zv[3]);
            *(float4*)(zr + 4) = make_float4(zv[4], zv[5], zv[6], zv[7]);
            if (tx == 0) { asrc[m] = p1; adst[m] = p2; }
        }
    }
}

// K2: per-edge logit + leaky_relu -> ebuf; segment max via atomicMax; dst histogram.
__global__ __launch_bounds__(256) void k_score(
        const float* __restrict__ ex, const int* __restrict__ src, const int* __restrict__ dst,
        const float* __restrict__ asrc, const float* __restrict__ adst,
        const float* __restrict__ u, const float* __restrict__ c0,
        float* __restrict__ ebuf, unsigned* __restrict__ menc, int* __restrict__ cnt, int E) {
    int i = blockIdx.x * 256 + threadIdx.x;
    if (i >= E) return;
    const float4* exr = (const float4*)(ex + (size_t)i * ED_D);
    const float4* u4 = (const float4*)u;
    float acc = 0.f;
#pragma unroll
    for (int q = 0; q < 16; ++q) {
        float4 a = exr[q], b = u4[q];
        acc += a.x * b.x + a.y * b.y + a.z * b.z + a.w * b.w;
    }
    int s = src[i], t = dst[i];
    float e = acc + asrc[s] + adst[t] + c0[0];
    e = (e > 0.f) ? e : NEG * e;
    ebuf[i] = e;
    atomicMax(&menc[t], fenc(e));
    atomicAdd(&cnt[t], 1);
}

// K3: exclusive scan of cnt -> rowptr (single block).
__global__ __launch_bounds__(1024) void k_scan(const int* __restrict__ cnt,
                                               int* __restrict__ rowptr, int N) {
    int t = threadIdx.x;
    int per = (N + 1023) / 1024;
    int b0 = t * per, b1 = b0 + per;
    if (b0 > N) b0 = N;
    if (b1 > N) b1 = N;
    int s = 0;
    for (int i = b0; i < b1; ++i) s += cnt[i];
    int wl = t & 63, w = t >> 6;
    int v = s;
#pragma unroll
    for (int off = 1; off < 64; off <<= 1) {
        int a = __shfl_up(v, off);
        if (wl >= off) v += a;
    }
    __shared__ int wsum[16], woff[16];
    if (wl == 63) wsum[w] = v;
    __syncthreads();
    if (t == 0) { int r = 0; for (int i = 0; i < 16; ++i) { woff[i] = r; r += wsum[i]; } }
    __syncthreads();
    int run = woff[w] + v - s;
    for (int i = b0; i < b1; ++i) { rowptr[i] = run; run += cnt[i]; }
    if (t == 1023) rowptr[N] = run;
}

// K4: CSR bucket + w=exp(e-m) once + denom. Writes src_csr[pos], {w,e}->we_csr[pos].
__global__ __launch_bounds__(256) void k_fill2(
        const int* __restrict__ src, const int* __restrict__ dst,
        const float* __restrict__ ebuf, const unsigned* __restrict__ menc,
        const int* __restrict__ rowptr, int* __restrict__ fill,
        float* __restrict__ denom, int* __restrict__ src_csr, int2* __restrict__ we_csr, int E) {
    int i = blockIdx.x * 256 + threadIdx.x;
    if (i >= E) return;
    int d = dst[i];
    int pos = rowptr[d] + atomicAdd(&fill[d], 1);
    float w = expf(ebuf[i] - fdec(menc[d]));
    atomicAdd(&denom[d], w);
    src_csr[pos] = src[i];
    we_csr[pos] = make_int2(__float_as_int(w), i);
}

// K5: wave-per-node weighted accumulation. Meta loaded coalesced (64 edges/shot),
// broadcast via shfl; 4 independent row loads in flight per unrolled step.
__global__ __launch_bounds__(256) void k_gather(
        const float2* __restrict__ zf2, const float* __restrict__ ex,
        const int* __restrict__ src_csr, const int2* __restrict__ we_csr,
        const int* __restrict__ rowptr, const float* __restrict__ denom,
        float2* __restrict__ h2, float* __restrict__ alpha_out, float* __restrict__ xsum, int N) {
    int lane = threadIdx.x & 63;
    int wid = blockIdx.x * 4 + (threadIdx.x >> 6);
    int nw = gridDim.x * 4;
    for (int n = wid; n < N; n += nw) {
        int beg = rowptr[n], end = rowptr[n + 1];
        float rden = 1.f / denom[n];
        float2 accz = make_float2(0.f, 0.f);
        float accx = 0.f;
        for (int c = beg; c < end; c += 64) {
            int mcnt = end - c;
            if (mcnt > 64) mcnt = 64;
            float al = 0.f; int sl = 0, el = 0;
            if (lane < mcnt) {
                int2 me = we_csr[c + lane];
                al = __int_as_float(me.x) * rden;
                el = me.y;
                sl = src_csr[c + lane];
                alpha_out[el] = al;
            }
            int j = 0;
            for (; j + 4 <= mcnt; j += 4) {
                float a[4]; int s[4], e[4];
#pragma unroll
                for (int q = 0; q < 4; ++q) {
                    a[q] = __shfl(al, j + q);
                    s[q] = __shfl(sl, j + q);
                    e[q] = __shfl(el, j + q);
                }
                float2 zv[4]; float xv[4];
#pragma unroll
                for (int q = 0; q < 4; ++q) {
                    zv[q] = zf2[(size_t)s[q] * 64 + lane];
                    xv[q] = ex[(size_t)e[q] * 64 + lane];
                }
#pragma unroll
                for (int q = 0; q < 4; ++q) {
                    accz.x = fmaf(a[q], zv[q].x, accz.x);
                    accz.y = fmaf(a[q], zv[q].y, accz.y);
                    accx = fmaf(a[q], xv[q], accx);
                }
            }
            for (; j < mcnt; ++j) {
                float aq = __shfl(al, j);
                int sq = __shfl(sl, j), eq = __shfl(el, j);
                float2 zq = zf2[(size_t)sq * 64 + lane];
                float xq = ex[(size_t)eq * 64 + lane];
                accz.x = fmaf(aq, zq.x, accz.x);
                accz.y = fmaf(aq, zq.y, accz.y);
                accx = fmaf(aq, xq, accx);
            }
        }
        h2[(size_t)n * 64 + lane] = accz;
        xsum[(size_t)n * 64 + lane] = accx;
    }
}

// K6: h = accz + Wt@xsum + b_edge (or 0 for empty segments). Wt staged in LDS.
__global__ __launch_bounds__(128) void k_xmm(
        const float* __restrict__ Wt, const float* __restrict__ b_edge,
        const float* __restrict__ xsum, const float* __restrict__ denom,
        float* __restrict__ h, int N) {
    __shared__ float wt[ED_D * OUT_D];
    int t = threadIdx.x;
    for (int i = t; i < ED_D * OUT_D; i += 128) wt[i] = Wt[i];
    __syncthreads();
    int lane = t & 63;
    float be = b_edge[t];
    for (int n = blockIdx.x; n < N; n += gridDim.x) {
        float xk = xsum[(size_t)n * ED_D + lane];
        float dn = denom[n];
        float hv = h[(size_t)n * OUT_D + t];
#pragma unroll 8
        for (int k = 0; k < ED_D; ++k) {
            hv = fmaf(wt[k * OUT_D + t], __shfl(xk, k), hv);
        }
        h[(size_t)n * OUT_D + t] = (dn != 0.f) ? (hv + be) : 0.f;
    }
}

extern "C" void kernel_launch(void* const* d_in, const int* in_sizes, int n_in,
                              void* d_out, int out_size, void* d_ws, size_t ws_size,
                              hipStream_t stream) {
    const float* nfeat = (const float*)d_in[0];
    const float* ex    = (const float*)d_in[1];
    const int*   src   = (const int*)d_in[2];
    const int*   dst   = (const int*)d_in[3];
    const float* W_fc  = (const float*)d_in[4];
    const float* b_fc  = (const float*)d_in[5];
    const float* W_att = (const float*)d_in[6];
    const float* b_att = (const float*)d_in[7];
    const float* W_edge = (const float*)d_in[8];
    const float* b_edge = (const float*)d_in[9];
    const float* W_eatt = (const float*)d_in[10];
    const float* b_eatt = (const float*)d_in[11];
    int N = in_sizes[0] / IN_D;
    int E = in_sizes[2];

    float* h_out = (float*)d_out;
    float* alpha_out = h_out + (size_t)N * OUT_D;

    char* w = (char*)d_ws;
    auto alloc = [&](size_t bytes) { char* p = w; w += (bytes + 255) & ~255ull; return p; };
    float* z      = (float*)alloc((size_t)N * OUT_D * 4);
    float* asrc   = (float*)alloc((size_t)N * 4);
    float* adst   = (float*)alloc((size_t)N * 4);
    float* ebuf   = (float*)alloc((size_t)E * 4);
    int* cnt      = (int*)alloc((size_t)N * 4);
    int* rowptr   = (int*)alloc(((size_t)N + 1) * 4);
    int* fill     = (int*)alloc((size_t)N * 4);
    unsigned* menc= (unsigned*)alloc((size_t)N * 4);
    float* denom  = (float*)alloc((size_t)N * 4);
    int* src_csr  = (int*)alloc((size_t)E * 4);
    int2* we_csr  = (int2*)alloc((size_t)E * 8);
    float* xsum   = (float*)alloc((size_t)N * ED_D * 4);
    float* Wt     = (float*)alloc((size_t)ED_D * OUT_D * 4);
    float* Wt_fc  = (float*)alloc((size_t)IN_D * OUT_D * 4);
    float* u      = (float*)alloc(64 * 4);
    float* c0     = (float*)alloc(4);

    hipMemsetAsync(cnt, 0, (size_t)N * 4, stream);
    hipMemsetAsync(fill, 0, (size_t)N * 4, stream);
    hipMemsetAsync(menc, 0, (size_t)N * 4, stream);
    hipMemsetAsync(denom, 0, (size_t)N * 4, stream);

    k_prep<<<1, 128, 0, stream>>>(W_att, b_att, W_eatt, b_eatt, W_edge, u, c0, Wt);
    k_tr<<<(IN_D * OUT_D) / 256, 256, 0, stream>>>(W_fc, Wt_fc);
    k_node<<<(N + 127) / 128, 256, 0, stream>>>(nfeat, Wt_fc, b_fc, W_att, z, asrc, adst, N);
    k_score<<<(E + 255) / 256, 256, 0, stream>>>(ex, src, dst, asrc, adst, u, c0, ebuf, menc, cnt, E);
    k_scan<<<1, 1024, 0, stream>>>(cnt, rowptr, N);
    k_fill2<<<(E + 255) / 256, 256, 0, stream>>>(src, dst, ebuf, menc, rowptr, fill, denom,
                                                 src_csr, we_csr, E);
    k_gather<<<(N + 3) / 4, 256, 0, stream>>>((const float2*)z, ex, src_csr, we_csr, rowptr,
                                              denom, (float2*)h_out, alpha_out, xsum, N);
    k_xmm<<<2048, 128, 0, stream>>>(Wt, b_edge, xsum, denom, h_out, N);
}

// Round 5
// 462.983 us; speedup vs baseline: 2.8639x; 1.1324x over previous
//
#include <hip/hip_runtime.h>
#include <math.h>
#include <float.h>

#define IN_D 256
#define OUT_D 128
#define ED_D 64
#define NEG 0.2f

__device__ __forceinline__ unsigned fenc(float f) {
    unsigned u = __float_as_uint(f);
    return (u & 0x80000000u) ? ~u : (u | 0x80000000u);
}
__device__ __forceinline__ float fdec(unsigned x) {
    return (x & 0x80000000u) ? __uint_as_float(x & 0x7fffffffu) : __uint_as_float(~x);
}

// K0: zero cnt/fill/menc; transpose W_fc -> Wt_fc; build Wt2 (W_edge^T in float2 [k][l]
// layout for k_gather's LDS matvec); fold attention's ex_t branch into u, c0.
__global__ __launch_bounds__(256) void k_init(
        const float* __restrict__ W_att, const float* __restrict__ b_att,
        const float* __restrict__ W_eatt, const float* __restrict__ b_eatt,
        const float* __restrict__ W_fc, const float* __restrict__ W_edge,
        float* __restrict__ u, float* __restrict__ c0,
        float* __restrict__ Wt_fc, float2* __restrict__ Wt2,
        int* __restrict__ cnt, int* __restrict__ fill, unsigned* __restrict__ menc, int N) {
    int idx = blockIdx.x * 256 + threadIdx.x;
    if (idx < N) { cnt[idx] = 0; fill[idx] = 0; menc[idx] = 0u; }
    if (idx < IN_D * OUT_D) {                 // 32768: Wt_fc[k][d] = W_fc[d][k]
        int k = idx >> 7, d = idx & 127;
        Wt_fc[idx] = W_fc[d * IN_D + k];
    }
    if (idx < ED_D * (OUT_D / 2)) {           // 4096: Wt2[k*64+l] = {We[2l][k], We[2l+1][k]}
        int k = idx >> 6, l = idx & 63;
        Wt2[idx] = make_float2(W_edge[(2 * l) * ED_D + k], W_edge[(2 * l + 1) * ED_D + k]);
    }
    if (idx < ED_D) {
        float acc = 0.f;
        for (int j = 0; j < ED_D; ++j) acc += W_att[256 + j] * W_eatt[j * ED_D + idx];
        u[idx] = acc;
    }
    if (idx == ED_D) {
        float c = 0.f;
        for (int j = 0; j < ED_D; ++j) c += W_att[256 + j] * b_eatt[j];
        c0[0] = c + b_att[0];
    }
}

// K1: dst-degree histogram (cheap: 3.2 MB stream).
__global__ __launch_bounds__(256) void k_hist(const int* __restrict__ dst,
                                              int* __restrict__ cnt, int E) {
    int i = blockIdx.x * 256 + threadIdx.x;
    if (i < E) atomicAdd(&cnt[dst[i]], 1);
}

// K2: tiled f32 GEMM  z = nfeat @ W_fc^T + b_fc  [N,128]
// BM=128, BN=128, BK=32; 256 threads; 8x8 register tile per thread.
// Epilogue: asrc[m] = z[m].w1, adst[m] = z[m].w2 via in-wave shuffle reduce (plain stores).
__global__ __launch_bounds__(256) void k_node(
        const float* __restrict__ nfeat, const float* __restrict__ Wt_fc,
        const float* __restrict__ b_fc, const float* __restrict__ W_att,
        float* __restrict__ z, float* __restrict__ asrc, float* __restrict__ adst, int n) {
    __shared__ float sa[32][130];
    __shared__ float sb[32][128];
    int t = threadIdx.x;
    int tx = t & 15, ty = t >> 4;
    int row_base = blockIdx.x * 128;

    float acc[8][8];
#pragma unroll
    for (int i = 0; i < 8; ++i)
#pragma unroll
        for (int j = 0; j < 8; ++j) acc[i][j] = 0.f;

    int ar = t >> 3, af = t & 7;
    int bk = t >> 5, bn = t & 31;

    for (int k0 = 0; k0 < IN_D; k0 += 32) {
#pragma unroll
        for (int p = 0; p < 4; ++p) {
            int r = ar + p * 32;
            int node = row_base + r; if (node >= n) node = n - 1;
            float4 v = *(const float4*)(nfeat + (size_t)node * IN_D + k0 + af * 4);
            sa[af * 4 + 0][r] = v.x;
            sa[af * 4 + 1][r] = v.y;
            sa[af * 4 + 2][r] = v.z;
            sa[af * 4 + 3][r] = v.w;
        }
#pragma unroll
        for (int p = 0; p < 4; ++p) {
            int kk = bk + p * 8;
            float4 v = *(const float4*)(Wt_fc + (size_t)(k0 + kk) * 128 + bn * 4);
            *(float4*)&sb[kk][bn * 4] = v;
        }
        __syncthreads();
#pragma unroll 8
        for (int kk = 0; kk < 32; ++kk) {
            float a0[8], b0[8];
            *(float4*)&a0[0] = *(const float4*)&sa[kk][ty * 8];
            *(float4*)&a0[4] = *(const float4*)&sa[kk][ty * 8 + 4];
            *(float4*)&b0[0] = *(const float4*)&sb[kk][tx * 8];
            *(float4*)&b0[4] = *(const float4*)&sb[kk][tx * 8 + 4];
#pragma unroll
            for (int i = 0; i < 8; ++i)
#pragma unroll
                for (int j = 0; j < 8; ++j)
                    acc[i][j] = fmaf(a0[i], b0[j], acc[i][j]);
        }
        __syncthreads();
    }

    float w1v[8], w2v[8], bf[8];
#pragma unroll
    for (int j = 0; j < 8; ++j) {
        int nn = tx * 8 + j;
        w1v[j] = W_att[nn];
        w2v[j] = W_att[128 + nn];
        bf[j] = b_fc[nn];
    }
#pragma unroll
    for (int i = 0; i < 8; ++i) {
        int m = row_base + ty * 8 + i;
        bool ok = (m < n);
        float zv[8];
        float p1 = 0.f, p2 = 0.f;
#pragma unroll
        for (int j = 0; j < 8; ++j) {
            zv[j] = acc[i][j] + bf[j];
            p1 = fmaf(zv[j], w1v[j], p1);
            p2 = fmaf(zv[j], w2v[j], p2);
        }
#pragma unroll
        for (int off = 1; off <= 8; off <<= 1) {
            p1 += __shfl_xor(p1, off);
            p2 += __shfl_xor(p2, off);
        }
        if (ok) {
            float* zr = z + (size_t)m * OUT_D + tx * 8;
            *(float4*)zr = make_float4(zv[0], zv[1], zv[2], zv[3]);
            *(float4*)(zr + 4) = make_float4(zv[4], zv[5], zv[6], zv[7]);
            if (tx == 0) { asrc[m] = p1; adst[m] = p2; }
        }
    }
}

// K3: exclusive scan of cnt -> rowptr (single block).
__global__ __launch_bounds__(1024) void k_scan(const int* __restrict__ cnt,
                                               int* __restrict__ rowptr, int N) {
    int t = threadIdx.x;
    int per = (N + 1023) / 1024;
    int b0 = t * per, b1 = b0 + per;
    if (b0 > N) b0 = N;
    if (b1 > N) b1 = N;
    int s = 0;
    for (int i = b0; i < b1; ++i) s += cnt[i];
    int wl = t & 63, w = t >> 6;
    int v = s;
#pragma unroll
    for (int off = 1; off < 64; off <<= 1) {
        int a = __shfl_up(v, off);
        if (wl >= off) v += a;
    }
    __shared__ int wsum[16], woff[16];
    if (wl == 63) wsum[w] = v;
    __syncthreads();
    if (t == 0) { int r = 0; for (int i = 0; i < 16; ++i) { woff[i] = r; r += wsum[i]; } }
    __syncthreads();
    int run = woff[w] + v - s;
    for (int i = b0; i < b1; ++i) { rowptr[i] = run; run += cnt[i]; }
    if (t == 1023) rowptr[N] = run;
}

// K4 (merged score+fill): per-edge logit + leaky_relu; bucket into CSR carrying the raw
// logit; segment max via atomicMax. No ebuf, no denom atomic (denom done in k_gather).
__global__ __launch_bounds__(256) void k_edge(
        const float* __restrict__ ex, const int* __restrict__ src, const int* __restrict__ dst,
        const float* __restrict__ asrc, const float* __restrict__ adst,
        const float* __restrict__ u, const float* __restrict__ c0,
        const int* __restrict__ rowptr, int* __restrict__ fill, unsigned* __restrict__ menc,
        int* __restrict__ src_csr, int2* __restrict__ we_csr, int E) {
    int i = blockIdx.x * 256 + threadIdx.x;
    if (i >= E) return;
    const float4* exr = (const float4*)(ex + (size_t)i * ED_D);
    const float4* u4 = (const float4*)u;
    float acc = 0.f;
#pragma unroll
    for (int q = 0; q < 16; ++q) {
        float4 a = exr[q], b = u4[q];
        acc += a.x * b.x + a.y * b.y + a.z * b.z + a.w * b.w;
    }
    int s = src[i], d = dst[i];
    float e = acc + asrc[s] + adst[d] + c0[0];
    e = (e > 0.f) ? e : NEG * e;
    int pos = rowptr[d] + atomicAdd(&fill[d], 1);
    src_csr[pos] = s;
    we_csr[pos] = make_int2(__float_as_int(e), i);
    atomicMax(&menc[d], fenc(e));
}

// K5 (fused gather + edge-matvec): wave-per-node. Phase 1: denom = sum exp(e-m).
// Phase 2: alpha writes + accz (z rows) + accx (ex rows). Epilogue: h = accz +
// W_edge@accx + b_edge via LDS-staged W_edge^T and shfl broadcast of accx lanes.
__global__ __launch_bounds__(256) void k_gather(
        const float2* __restrict__ zf2, const float* __restrict__ ex,
        const int* __restrict__ src_csr, const int2* __restrict__ we_csr,
        const int* __restrict__ rowptr, const unsigned* __restrict__ menc,
        const float2* __restrict__ Wt2, const float* __restrict__ b_edge,
        float2* __restrict__ h2, float* __restrict__ alpha_out, int N) {
    __shared__ float2 swt[ED_D * 64];   // [k][l] pairs: 32 KB, 2-way-free ds_read_b64
    for (int i = threadIdx.x; i < ED_D * 64; i += 256) swt[i] = Wt2[i];
    __syncthreads();
    int lane = threadIdx.x & 63;
    int wid = blockIdx.x * 4 + (threadIdx.x >> 6);
    int nw = gridDim.x * 4;
    float2 be2 = ((const float2*)b_edge)[lane];
    for (int n = wid; n < N; n += nw) {
        int beg = rowptr[n], end = rowptr[n + 1];
        float m = fdec(menc[n]);
        // phase 1: denominator (coalesced pass over this segment's logits)
        float sw = 0.f;
        for (int c = beg + lane; c < end; c += 64)
            sw += expf(__int_as_float(we_csr[c].x) - m);
#pragma unroll
        for (int off = 32; off >= 1; off >>= 1) sw += __shfl_xor(sw, off);
        float dn = sw;
        float rden = 1.f / dn;
        // phase 2: weighted accumulation
        float2 accz = make_float2(0.f, 0.f);
        float accx = 0.f;
        for (int c = beg; c < end; c += 64) {
            int mcnt = end - c;
            if (mcnt > 64) mcnt = 64;
            float al = 0.f; int sl = 0, el = 0;
            if (lane < mcnt) {
                int2 me = we_csr[c + lane];
                al = expf(__int_as_float(me.x) - m) * rden;
                el = me.y;
                sl = src_csr[c + lane];
                alpha_out[el] = al;
            }
            int j = 0;
            for (; j + 4 <= mcnt; j += 4) {
                float a[4]; int s[4], e[4];
#pragma unroll
                for (int q = 0; q < 4; ++q) {
                    a[q] = __shfl(al, j + q);
                    s[q] = __shfl(sl, j + q);
                    e[q] = __shfl(el, j + q);
                }
                float2 zv[4]; float xv[4];
#pragma unroll
                for (int q = 0; q < 4; ++q) {
                    zv[q] = zf2[(size_t)s[q] * 64 + lane];
                    xv[q] = ex[(size_t)e[q] * 64 + lane];
                }
#pragma unroll
                for (int q = 0; q < 4; ++q) {
                    accz.x = fmaf(a[q], zv[q].x, accz.x);
                    accz.y = fmaf(a[q], zv[q].y, accz.y);
                    accx = fmaf(a[q], xv[q], accx);
                }
            }
            for (; j < mcnt; ++j) {
                float aq = __shfl(al, j);
                int sq = __shfl(sl, j), eq = __shfl(el, j);
                float2 zq = zf2[(size_t)sq * 64 + lane];
                float xq = ex[(size_t)eq * 64 + lane];
                accz.x = fmaf(aq, zq.x, accz.x);
                accz.y = fmaf(aq, zq.y, accz.y);
                accx = fmaf(aq, xq, accx);
            }
        }
        // epilogue: h = accz + W_edge @ accx + b_edge  (accx[k] lives in lane k)
        float2 hv = make_float2(accz.x + be2.x, accz.y + be2.y);
#pragma unroll 8
        for (int k = 0; k < 64; ++k) {
            float a = __shfl(accx, k);
            float2 w2 = swt[k * 64 + lane];
            hv.x = fmaf(a, w2.x, hv.x);
            hv.y = fmaf(a, w2.y, hv.y);
        }
        if (dn == 0.f) hv = make_float2(0.f, 0.f);   // empty segment -> 0 (ref semantics)
        h2[(size_t)n * 64 + lane] = hv;
    }
}

extern "C" void kernel_launch(void* const* d_in, const int* in_sizes, int n_in,
                              void* d_out, int out_size, void* d_ws, size_t ws_size,
                              hipStream_t stream) {
    const float* nfeat = (const float*)d_in[0];
    const float* ex    = (const float*)d_in[1];
    const int*   src   = (const int*)d_in[2];
    const int*   dst   = (const int*)d_in[3];
    const float* W_fc  = (const float*)d_in[4];
    const float* b_fc  = (const float*)d_in[5];
    const float* W_att = (const float*)d_in[6];
    const float* b_att = (const float*)d_in[7];
    const float* W_edge = (const float*)d_in[8];
    const float* b_edge = (const float*)d_in[9];
    const float* W_eatt = (const float*)d_in[10];
    const float* b_eatt = (const float*)d_in[11];
    int N = in_sizes[0] / IN_D;
    int E = in_sizes[2];

    float* h_out = (float*)d_out;
    float* alpha_out = h_out + (size_t)N * OUT_D;

    char* w = (char*)d_ws;
    auto alloc = [&](size_t bytes) { char* p = w; w += (bytes + 255) & ~255ull; return p; };
    float* z      = (float*)alloc((size_t)N * OUT_D * 4);
    float* asrc   = (float*)alloc((size_t)N * 4);
    float* adst   = (float*)alloc((size_t)N * 4);
    int* cnt      = (int*)alloc((size_t)N * 4);
    int* rowptr   = (int*)alloc(((size_t)N + 1) * 4);
    int* fill     = (int*)alloc((size_t)N * 4);
    unsigned* menc= (unsigned*)alloc((size_t)N * 4);
    int* src_csr  = (int*)alloc((size_t)E * 4);
    int2* we_csr  = (int2*)alloc((size_t)E * 8);
    float* Wt_fc  = (float*)alloc((size_t)IN_D * OUT_D * 4);
    float2* Wt2   = (float2*)alloc((size_t)ED_D * 64 * 8);
    float* u      = (float*)alloc(64 * 4);
    float* c0     = (float*)alloc(4);

    int init_total = N > IN_D * OUT_D ? N : IN_D * OUT_D;
    k_init<<<(init_total + 255) / 256, 256, 0, stream>>>(
        W_att, b_att, W_eatt, b_eatt, W_fc, W_edge, u, c0, Wt_fc, Wt2, cnt, fill, menc, N);
    k_hist<<<(E + 255) / 256, 256, 0, stream>>>(dst, cnt, E);
    k_node<<<(N + 127) / 128, 256, 0, stream>>>(nfeat, Wt_fc, b_fc, W_att, z, asrc, adst, N);
    k_scan<<<1, 1024, 0, stream>>>(cnt, rowptr, N);
    k_edge<<<(E + 255) / 256, 256, 0, stream>>>(ex, src, dst, asrc, adst, u, c0,
                                                rowptr, fill, menc, src_csr, we_csr, E);
    k_gather<<<(N + 3) / 4, 256, 0, stream>>>((const float2*)z, ex, src_csr, we_csr, rowptr,
                                              menc, (const float2*)Wt2, b_edge,
                                              (float2*)h_out, alpha_out, N);
}

// Round 6
// 430.512 us; speedup vs baseline: 3.0799x; 1.0754x over previous
//
#include <hip/hip_runtime.h>
#include <math.h>
#include <float.h>

#define IN_D 256
#define OUT_D 128
#define ED_D 64
#define NEG 0.2f

// K0: zero cnt/fill; transpose W_fc -> Wt_fc; build Wt2 (W_edge^T as float2 [k][l]);
// fold attention's ex_t branch into u, c0.
__global__ __launch_bounds__(256) void k_init(
        const float* __restrict__ W_att, const float* __restrict__ b_att,
        const float* __restrict__ W_eatt, const float* __restrict__ b_eatt,
        const float* __restrict__ W_fc, const float* __restrict__ W_edge,
        float* __restrict__ u, float* __restrict__ c0,
        float* __restrict__ Wt_fc, float2* __restrict__ Wt2,
        int* __restrict__ cnt, int* __restrict__ fill, int N) {
    int idx = blockIdx.x * 256 + threadIdx.x;
    if (idx < N) { cnt[idx] = 0; fill[idx] = 0; }
    if (idx < IN_D * OUT_D) {                 // 32768: Wt_fc[k][d] = W_fc[d][k]
        int k = idx >> 7, d = idx & 127;
        Wt_fc[idx] = W_fc[d * IN_D + k];
    }
    if (idx < ED_D * (OUT_D / 2)) {           // 4096: Wt2[k*64+l] = {We[2l][k], We[2l+1][k]}
        int k = idx >> 6, l = idx & 63;
        Wt2[idx] = make_float2(W_edge[(2 * l) * ED_D + k], W_edge[(2 * l + 1) * ED_D + k]);
    }
    if (idx < ED_D) {
        float acc = 0.f;
        for (int j = 0; j < ED_D; ++j) acc += W_att[256 + j] * W_eatt[j * ED_D + idx];
        u[idx] = acc;
    }
    if (idx == ED_D) {
        float c = 0.f;
        for (int j = 0; j < ED_D; ++j) c += W_att[256 + j] * b_eatt[j];
        c0[0] = c + b_att[0];
    }
}

// K1: dst-degree histogram.
__global__ __launch_bounds__(256) void k_hist(const int* __restrict__ dst,
                                              int* __restrict__ cnt, int E) {
    int i = blockIdx.x * 256 + threadIdx.x;
    if (i < E) atomicAdd(&cnt[dst[i]], 1);
}

// K2: tiled f32 GEMM  z = nfeat @ W_fc^T + b_fc  [N,128]
// BM=128, BN=128, BK=32; 256 threads; 8x8 register tile per thread.
// Epilogue: asrc[m]=z[m].w1, adst[m]=z[m].w2 via in-wave shuffle reduce (plain stores).
__global__ __launch_bounds__(256) void k_node(
        const float* __restrict__ nfeat, const float* __restrict__ Wt_fc,
        const float* __restrict__ b_fc, const float* __restrict__ W_att,
        float* __restrict__ z, float* __restrict__ asrc, float* __restrict__ adst, int n) {
    __shared__ float sa[32][130];
    __shared__ float sb[32][128];
    int t = threadIdx.x;
    int tx = t & 15, ty = t >> 4;
    int row_base = blockIdx.x * 128;

    float acc[8][8];
#pragma unroll
    for (int i = 0; i < 8; ++i)
#pragma unroll
        for (int j = 0; j < 8; ++j) acc[i][j] = 0.f;

    int ar = t >> 3, af = t & 7;
    int bk = t >> 5, bn = t & 31;

    for (int k0 = 0; k0 < IN_D; k0 += 32) {
#pragma unroll
        for (int p = 0; p < 4; ++p) {
            int r = ar + p * 32;
            int node = row_base + r; if (node >= n) node = n - 1;
            float4 v = *(const float4*)(nfeat + (size_t)node * IN_D + k0 + af * 4);
            sa[af * 4 + 0][r] = v.x;
            sa[af * 4 + 1][r] = v.y;
            sa[af * 4 + 2][r] = v.z;
            sa[af * 4 + 3][r] = v.w;
        }
#pragma unroll
        for (int p = 0; p < 4; ++p) {
            int kk = bk + p * 8;
            float4 v = *(const float4*)(Wt_fc + (size_t)(k0 + kk) * 128 + bn * 4);
            *(float4*)&sb[kk][bn * 4] = v;
        }
        __syncthreads();
#pragma unroll 8
        for (int kk = 0; kk < 32; ++kk) {
            float a0[8], b0[8];
            *(float4*)&a0[0] = *(const float4*)&sa[kk][ty * 8];
            *(float4*)&a0[4] = *(const float4*)&sa[kk][ty * 8 + 4];
            *(float4*)&b0[0] = *(const float4*)&sb[kk][tx * 8];
            *(float4*)&b0[4] = *(const float4*)&sb[kk][tx * 8 + 4];
#pragma unroll
            for (int i = 0; i < 8; ++i)
#pragma unroll
                for (int j = 0; j < 8; ++j)
                    acc[i][j] = fmaf(a0[i], b0[j], acc[i][j]);
        }
        __syncthreads();
    }

    float w1v[8], w2v[8], bf[8];
#pragma unroll
    for (int j = 0; j < 8; ++j) {
        int nn = tx * 8 + j;
        w1v[j] = W_att[nn];
        w2v[j] = W_att[128 + nn];
        bf[j] = b_fc[nn];
    }
#pragma unroll
    for (int i = 0; i < 8; ++i) {
        int m = row_base + ty * 8 + i;
        bool ok = (m < n);
        float zv[8];
        float p1 = 0.f, p2 = 0.f;
#pragma unroll
        for (int j = 0; j < 8; ++j) {
            zv[j] = acc[i][j] + bf[j];
            p1 = fmaf(zv[j], w1v[j], p1);
            p2 = fmaf(zv[j], w2v[j], p2);
        }
#pragma unroll
        for (int off = 1; off <= 8; off <<= 1) {
            p1 += __shfl_xor(p1, off);
            p2 += __shfl_xor(p2, off);
        }
        if (ok) {
            float* zr = z + (size_t)m * OUT_D + tx * 8;
            *(float4*)zr = make_float4(zv[0], zv[1], zv[2], zv[3]);
            *(float4*)(zr + 4) = make_float4(zv[4], zv[5], zv[6], zv[7]);
            if (tx == 0) { asrc[m] = p1; adst[m] = p2; }
        }
    }
}

// K3: exclusive scan of cnt -> rowptr (single block).
__global__ __launch_bounds__(1024) void k_scan(const int* __restrict__ cnt,
                                               int* __restrict__ rowptr, int N) {
    int t = threadIdx.x;
    int per = (N + 1023) / 1024;
    int b0 = t * per, b1 = b0 + per;
    if (b0 > N) b0 = N;
    if (b1 > N) b1 = N;
    int s = 0;
    for (int i = b0; i < b1; ++i) s += cnt[i];
    int wl = t & 63, w = t >> 6;
    int v = s;
#pragma unroll
    for (int off = 1; off < 64; off <<= 1) {
        int a = __shfl_up(v, off);
        if (wl >= off) v += a;
    }
    __shared__ int wsum[16], woff[16];
    if (wl == 63) wsum[w] = v;
    __syncthreads();
    if (t == 0) { int r = 0; for (int i = 0; i < 16; ++i) { woff[i] = r; r += wsum[i]; } }
    __syncthreads();
    int run = woff[w] + v - s;
    for (int i = b0; i < b1; ++i) { rowptr[i] = run; run += cnt[i]; }
    if (t == 1023) rowptr[N] = run;
}

// K4: per-edge logit + leaky_relu; bucket {logit, eid, src} into CSR. No atomicMax
// (segment max is computed wave-locally in k_gather).
__global__ __launch_bounds__(256) void k_edge(
        const float* __restrict__ ex, const int* __restrict__ src, const int* __restrict__ dst,
        const float* __restrict__ asrc, const float* __restrict__ adst,
        const float* __restrict__ u, const float* __restrict__ c0,
        const int* __restrict__ rowptr, int* __restrict__ fill,
        int4* __restrict__ csr, int E) {
    int i = blockIdx.x * 256 + threadIdx.x;
    if (i >= E) return;
    const float4* exr = (const float4*)(ex + (size_t)i * ED_D);
    const float4* u4 = (const float4*)u;
    float acc = 0.f;
#pragma unroll
    for (int q = 0; q < 16; ++q) {
        float4 a = exr[q], b = u4[q];
        acc += a.x * b.x + a.y * b.y + a.z * b.z + a.w * b.w;
    }
    int s = src[i], d = dst[i];
    float e = acc + asrc[s] + adst[d] + c0[0];
    e = (e > 0.f) ? e : NEG * e;
    int pos = rowptr[d] + atomicAdd(&fill[d], 1);
    csr[pos] = make_int4(__float_as_int(e), i, s, 0);
}

// K5: wave-per-node, single pass. Fast path (deg<=64): lane=edge; wave-local max/sum,
// alpha from registers; 8-deep row-gather ILP. Epilogue: h = accz + W_edge@accx + b_edge
// via LDS-staged W_edge^T and shfl broadcast of accx lanes.
__global__ __launch_bounds__(256) void k_gather(
        const float2* __restrict__ zf2, const float* __restrict__ ex,
        const int4* __restrict__ csr, const int* __restrict__ rowptr,
        const float2* __restrict__ Wt2, const float* __restrict__ b_edge,
        float2* __restrict__ h2, float* __restrict__ alpha_out, int N) {
    __shared__ float2 swt[ED_D * 64];   // 32 KB
    for (int i = threadIdx.x; i < ED_D * 64; i += 256) swt[i] = Wt2[i];
    __syncthreads();
    int lane = threadIdx.x & 63;
    int wid = blockIdx.x * 4 + (threadIdx.x >> 6);
    int nw = gridDim.x * 4;
    float2 be2 = ((const float2*)b_edge)[lane];
    for (int n = wid; n < N; n += nw) {
        int beg = rowptr[n], end = rowptr[n + 1];
        int deg = end - beg;
        if (deg == 0) {                      // empty segment -> 0 (ref semantics)
            h2[(size_t)n * 64 + lane] = make_float2(0.f, 0.f);
            continue;
        }
        float2 accz = make_float2(0.f, 0.f);
        float accx = 0.f;
        if (deg <= 64) {
            int4 me = make_int4(0, 0, 0, 0);
            float lg = -FLT_MAX;
            if (lane < deg) { me = csr[beg + lane]; lg = __int_as_float(me.x); }
            float m = lg;
#pragma unroll
            for (int off = 32; off >= 1; off >>= 1) m = fmaxf(m, __shfl_xor(m, off));
            float wv = (lane < deg) ? expf(lg - m) : 0.f;
            float sw = wv;
#pragma unroll
            for (int off = 32; off >= 1; off >>= 1) sw += __shfl_xor(sw, off);
            float al = wv / sw;
            if (lane < deg) alpha_out[me.y] = al;
            int j = 0;
            for (; j + 8 <= deg; j += 8) {
                float a[8]; int s[8], e[8];
#pragma unroll
                for (int q = 0; q < 8; ++q) {
                    a[q] = __shfl(al, j + q);
                    s[q] = __shfl(me.z, j + q);
                    e[q] = __shfl(me.y, j + q);
                }
                float2 zv[8]; float xv[8];
#pragma unroll
                for (int q = 0; q < 8; ++q) {
                    zv[q] = zf2[(size_t)s[q] * 64 + lane];
                    xv[q] = ex[(size_t)e[q] * 64 + lane];
                }
#pragma unroll
                for (int q = 0; q < 8; ++q) {
                    accz.x = fmaf(a[q], zv[q].x, accz.x);
                    accz.y = fmaf(a[q], zv[q].y, accz.y);
                    accx = fmaf(a[q], xv[q], accx);
                }
            }
            for (; j + 4 <= deg; j += 4) {
                float a[4]; int s[4], e[4];
#pragma unroll
                for (int q = 0; q < 4; ++q) {
                    a[q] = __shfl(al, j + q);
                    s[q] = __shfl(me.z, j + q);
                    e[q] = __shfl(me.y, j + q);
                }
                float2 zv[4]; float xv[4];
#pragma unroll
                for (int q = 0; q < 4; ++q) {
                    zv[q] = zf2[(size_t)s[q] * 64 + lane];
                    xv[q] = ex[(size_t)e[q] * 64 + lane];
                }
#pragma unroll
                for (int q = 0; q < 4; ++q) {
                    accz.x = fmaf(a[q], zv[q].x, accz.x);
                    accz.y = fmaf(a[q], zv[q].y, accz.y);
                    accx = fmaf(a[q], xv[q], accx);
                }
            }
            for (; j < deg; ++j) {
                float aq = __shfl(al, j);
                int sq = __shfl(me.z, j), eq = __shfl(me.y, j);
                float2 zq = zf2[(size_t)sq * 64 + lane];
                float xq = ex[(size_t)eq * 64 + lane];
                accz.x = fmaf(aq, zq.x, accz.x);
                accz.y = fmaf(aq, zq.y, accz.y);
                accx = fmaf(aq, xq, accx);
            }
        } else {
            // rare slow path: chunked 3-pass
            float m = -FLT_MAX;
            for (int c = beg + lane; c < end; c += 64)
                m = fmaxf(m, __int_as_float(csr[c].x));
#pragma unroll
            for (int off = 32; off >= 1; off >>= 1) m = fmaxf(m, __shfl_xor(m, off));
            float sw = 0.f;
            for (int c = beg + lane; c < end; c += 64)
                sw += expf(__int_as_float(csr[c].x) - m);
#pragma unroll
            for (int off = 32; off >= 1; off >>= 1) sw += __shfl_xor(sw, off);
            float rden = 1.f / sw;
            for (int c = beg; c < end; c += 64) {
                int mcnt = end - c;
                if (mcnt > 64) mcnt = 64;
                int4 me = make_int4(0, 0, 0, 0);
                float al = 0.f;
                if (lane < mcnt) {
                    me = csr[c + lane];
                    al = expf(__int_as_float(me.x) - m) * rden;
                    alpha_out[me.y] = al;
                }
                int j = 0;
                for (; j + 4 <= mcnt; j += 4) {
                    float a[4]; int s[4], e[4];
#pragma unroll
                    for (int q = 0; q < 4; ++q) {
                        a[q] = __shfl(al, j + q);
                        s[q] = __shfl(me.z, j + q);
                        e[q] = __shfl(me.y, j + q);
                    }
                    float2 zv[4]; float xv[4];
#pragma unroll
                    for (int q = 0; q < 4; ++q) {
                        zv[q] = zf2[(size_t)s[q] * 64 + lane];
                        xv[q] = ex[(size_t)e[q] * 64 + lane];
                    }
#pragma unroll
                    for (int q = 0; q < 4; ++q) {
                        accz.x = fmaf(a[q], zv[q].x, accz.x);
                        accz.y = fmaf(a[q], zv[q].y, accz.y);
                        accx = fmaf(a[q], xv[q], accx);
                    }
                }
                for (; j < mcnt; ++j) {
                    float aq = __shfl(al, j);
                    int sq = __shfl(me.z, j), eq = __shfl(me.y, j);
                    float2 zq = zf2[(size_t)sq * 64 + lane];
                    float xq = ex[(size_t)eq * 64 + lane];
                    accz.x = fmaf(aq, zq.x, accz.x);
                    accz.y = fmaf(aq, zq.y, accz.y);
                    accx = fmaf(aq, xq, accx);
                }
            }
        }
        // epilogue: h = accz + W_edge @ accx + b_edge  (accx[k] lives in lane k)
        float2 hv = make_float2(accz.x + be2.x, accz.y + be2.y);
#pragma unroll 8
        for (int k = 0; k < 64; ++k) {
            float a = __shfl(accx, k);
            float2 w2 = swt[k * 64 + lane];
            hv.x = fmaf(a, w2.x, hv.x);
            hv.y = fmaf(a, w2.y, hv.y);
        }
        h2[(size_t)n * 64 + lane] = hv;
    }
}

extern "C" void kernel_launch(void* const* d_in, const int* in_sizes, int n_in,
                              void* d_out, int out_size, void* d_ws, size_t ws_size,
                              hipStream_t stream) {
    const float* nfeat = (const float*)d_in[0];
    const float* ex    = (const float*)d_in[1];
    const int*   src   = (const int*)d_in[2];
    const int*   dst   = (const int*)d_in[3];
    const float* W_fc  = (const float*)d_in[4];
    const float* b_fc  = (const float*)d_in[5];
    const float* W_att = (const float*)d_in[6];
    const float* b_att = (const float*)d_in[7];
    const float* W_edge = (const float*)d_in[8];
    const float* b_edge = (const float*)d_in[9];
    const float* W_eatt = (const float*)d_in[10];
    const float* b_eatt = (const float*)d_in[11];
    int N = in_sizes[0] / IN_D;
    int E = in_sizes[2];

    float* h_out = (float*)d_out;
    float* alpha_out = h_out + (size_t)N * OUT_D;

    char* w = (char*)d_ws;
    auto alloc = [&](size_t bytes) { char* p = w; w += (bytes + 255) & ~255ull; return p; };
    float* z      = (float*)alloc((size_t)N * OUT_D * 4);
    float* asrc   = (float*)alloc((size_t)N * 4);
    float* adst   = (float*)alloc((size_t)N * 4);
    int* cnt      = (int*)alloc((size_t)N * 4);
    int* rowptr   = (int*)alloc(((size_t)N + 1) * 4);
    int* fill     = (int*)alloc((size_t)N * 4);
    int4* csr     = (int4*)alloc((size_t)E * 16);
    float* Wt_fc  = (float*)alloc((size_t)IN_D * OUT_D * 4);
    float2* Wt2   = (float2*)alloc((size_t)ED_D * 64 * 8);
    float* u      = (float*)alloc(64 * 4);
    float* c0     = (float*)alloc(4);

    int init_total = N > IN_D * OUT_D ? N : IN_D * OUT_D;
    k_init<<<(init_total + 255) / 256, 256, 0, stream>>>(
        W_att, b_att, W_eatt, b_eatt, W_fc, W_edge, u, c0, Wt_fc, Wt2, cnt, fill, N);
    k_hist<<<(E + 255) / 256, 256, 0, stream>>>(dst, cnt, E);
    k_node<<<(N + 127) / 128, 256, 0, stream>>>(nfeat, Wt_fc, b_fc, W_att, z, asrc, adst, N);
    k_scan<<<1, 1024, 0, stream>>>(cnt, rowptr, N);
    k_edge<<<(E + 255) / 256, 256, 0, stream>>>(ex, src, dst, asrc, adst, u, c0,
                                                rowptr, fill, csr, E);
    k_gather<<<(N + 3) / 4, 256, 0, stream>>>((const float2*)z, ex, csr, rowptr,
                                              (const float2*)Wt2, b_edge,
                                              (float2*)h_out, alpha_out, N);
}